// Round 1
// baseline (258.423 us; speedup 1.0000x reference)
//
#include <hip/hip_runtime.h>

// Problem constants (from reference): x (128,1024) f32, weight (1024,1024) f32,
// bias (1024,) f32, T scalar. out (128,1024) f32 = bias[m] + relu(topk128sum(x[b]+w[m]) - T).
static constexpr int BDIM = 128;
static constexpr int NDIM = 1024;
static constexpr int MDIM = 1024;
static constexpr int KTOP = 128;
static constexpr int SPLIT = 8;              // b-chunks per m (waves per m)
static constexpr int BPC = BDIM / SPLIT;     // 16 b-values per wave

// One wave per (m, b-chunk). 16 values/lane held in registers.
// Exact top-K sum via bit-descent radix select on order-preserving uint keys,
// counts via wave ballot (scalar-pipe popcount), early exit when count==K.
__global__ __launch_bounds__(256) void topk_sum_kernel(
    const float* __restrict__ x, const float* __restrict__ w,
    const float* __restrict__ bias, const float* __restrict__ T,
    float* __restrict__ out)
{
  const int lane = threadIdx.x & 63;
  const int wg   = (int)((blockIdx.x * 256u + threadIdx.x) >> 6);
  const int m    = wg >> 3;                  // wg / SPLIT
  const int b0   = (wg & (SPLIT - 1)) * BPC;

  // Load this wave's weight row once: value n = c*256 + lane*4 + j (coalesced float4)
  float wv[16];
  {
    const float4* wrow = reinterpret_cast<const float4*>(w + (size_t)m * NDIM);
#pragma unroll
    for (int c = 0; c < 4; ++c) {
      float4 q = wrow[c * 64 + lane];
      wv[c*4+0] = q.x; wv[c*4+1] = q.y; wv[c*4+2] = q.z; wv[c*4+3] = q.w;
    }
  }
  const float Tv = T[0];
  const float bv = bias[m];

  for (int bi = 0; bi < BPC; ++bi) {
    const int b = b0 + bi;
    const float4* xrow = reinterpret_cast<const float4*>(x + (size_t)b * NDIM);

    float v[16];
    unsigned u[16];
#pragma unroll
    for (int c = 0; c < 4; ++c) {
      float4 q = xrow[c * 64 + lane];
      v[c*4+0] = q.x + wv[c*4+0];
      v[c*4+1] = q.y + wv[c*4+1];
      v[c*4+2] = q.z + wv[c*4+2];
      v[c*4+3] = q.w + wv[c*4+3];
    }
#pragma unroll
    for (int i = 0; i < 16; ++i) {
      unsigned bb = __float_as_uint(v[i]);
      // order-preserving map: neg -> ~bits, pos -> bits | 0x80000000
      u[i] = bb ^ ((unsigned)(((int)bb) >> 31) | 0x80000000u);
    }

    // Radix-1 descent for the Kth largest key; early exit when count == K.
    unsigned pfx = 0u, thr = 0u;
    bool found = false;
    for (int bit = 31; bit >= 0; --bit) {
      const unsigned cand = pfx | (1u << bit);
      int c = 0;
#pragma unroll
      for (int i = 0; i < 16; ++i)
        c += (int)__popcll(__ballot(u[i] >= cand));
      if (c == KTOP) { thr = cand; found = true; break; }
      if (c > KTOP) pfx = cand;
    }
    if (!found) thr = pfx;

    // Final pass: sum of strictly-greater values + exact tie correction.
    float s = 0.f;
    int cgt = 0;
#pragma unroll
    for (int i = 0; i < 16; ++i) {
      const bool g = (u[i] > thr);
      cgt += (int)__popcll(__ballot(g));
      s += g ? v[i] : 0.f;
    }
#pragma unroll
    for (int off = 32; off > 0; off >>= 1)
      s += __shfl_xor(s, off);

    const unsigned tb = (thr & 0x80000000u) ? (thr & 0x7fffffffu) : ~thr;
    const float tval = __uint_as_float(tb);
    const float extr = s + (float)(KTOP - cgt) * tval;
    const float r = bv + fmaxf(extr - Tv, 0.f);
    if (lane == 0) out[(size_t)b * MDIM + m] = r;
  }
}

extern "C" void kernel_launch(void* const* d_in, const int* in_sizes, int n_in,
                              void* d_out, int out_size, void* d_ws, size_t ws_size,
                              hipStream_t stream) {
  const float* x    = (const float*)d_in[0];
  const float* w    = (const float*)d_in[1];
  const float* bias = (const float*)d_in[2];
  const float* T    = (const float*)d_in[3];
  float* out = (float*)d_out;

  // M * SPLIT waves = 8192 waves = 2048 blocks of 4 waves.
  dim3 grid(MDIM * SPLIT / 4);
  topk_sum_kernel<<<grid, dim3(256), 0, stream>>>(x, w, bias, T, out);
}

// Round 2
// 215.147 us; speedup vs baseline: 1.2011x; 1.2011x over previous
//
#include <hip/hip_runtime.h>

// x (128,1024) f32, weight (1024,1024) f32, bias (1024,) f32, T (1,) f32.
// out (128,1024) f32 = bias[m] + relu(top128sum(x[b,:]+w[m,:]) - T).
static constexpr int BDIM = 128;
static constexpr int NDIM = 1024;
static constexpr int MDIM = 1024;
static constexpr int KTOP = 128;
static constexpr int SPLIT = 8;              // b-chunks per m (waves per m)
static constexpr int BPC = BDIM / SPLIT;     // 16 b-values per wave
static constexpr int P = 4;                  // pairs interleaved in lockstep

// Order-preserving key probes: key(f>0) = bits(f) | 0x80000000.
static constexpr unsigned KEY_2  = 0xC0000000u;  // 2.0f
static constexpr unsigned KEY_1  = 0xBF800000u;  // 1.0f
static constexpr unsigned KEY_H  = 0xBF000000u;  // 0.5f

__device__ __forceinline__ int cnt16ge(const unsigned (&u)[16], unsigned cand) {
  int c = 0;
#pragma unroll
  for (int i = 0; i < 16; ++i)
    c += (int)__popcll(__ballot(u[i] >= cand));
  return c;
}

__global__ __launch_bounds__(256) void topk_sum_kernel(
    const float* __restrict__ x, const float* __restrict__ w,
    const float* __restrict__ bias, const float* __restrict__ T,
    float* __restrict__ out)
{
  const int lane = threadIdx.x & 63;
  const int wg   = (int)((blockIdx.x * 256u + threadIdx.x) >> 6);
  const int m    = wg >> 3;                  // wg / SPLIT
  const int b0   = (wg & (SPLIT - 1)) * BPC;

  // Weight row resident in 16 VGPRs: value n = c*256 + lane*4 + j (coalesced)
  float wv[16];
  {
    const float4* wrow = reinterpret_cast<const float4*>(w + (size_t)m * NDIM);
#pragma unroll
    for (int c = 0; c < 4; ++c) {
      float4 q = wrow[c * 64 + lane];
      wv[c*4+0] = q.x; wv[c*4+1] = q.y; wv[c*4+2] = q.z; wv[c*4+3] = q.w;
    }
  }
  const float Tv = T[0];
  const float bv = bias[m];

  for (int g = 0; g < BPC; g += P) {
    // ---- load + add + key-transform for P pairs (independent → memory ILP)
    unsigned u[P][16];
#pragma unroll
    for (int p = 0; p < P; ++p) {
      const float4* xrow =
          reinterpret_cast<const float4*>(x + (size_t)(b0 + g + p) * NDIM);
#pragma unroll
      for (int c = 0; c < 4; ++c) {
        float4 q = xrow[c * 64 + lane];
        float a0 = q.x + wv[c*4+0], a1 = q.y + wv[c*4+1];
        float a2 = q.z + wv[c*4+2], a3 = q.w + wv[c*4+3];
        unsigned b0b = __float_as_uint(a0), b1b = __float_as_uint(a1);
        unsigned b2b = __float_as_uint(a2), b3b = __float_as_uint(a3);
        u[p][c*4+0] = b0b ^ ((unsigned)(((int)b0b) >> 31) | 0x80000000u);
        u[p][c*4+1] = b1b ^ ((unsigned)(((int)b1b) >> 31) | 0x80000000u);
        u[p][c*4+2] = b2b ^ ((unsigned)(((int)b2b) >> 31) | 0x80000000u);
        u[p][c*4+3] = b3b ^ ((unsigned)(((int)b3b) >> 31) | 0x80000000u);
      }
    }

    // ---- probe ladder: lock sign+exponent bits cheaply (exact, with fallback)
    unsigned pfx[P], thr[P];
    int sb[P];
    bool done[P];
#pragma unroll
    for (int p = 0; p < P; ++p) {
      done[p] = false; thr[p] = 0u;
      int c2 = cnt16ge(u[p], KEY_2);
      if (c2 >= KTOP) {
        if (c2 == KTOP) { thr[p] = KEY_2; done[p] = true; sb[p] = 0; }
        else           { pfx[p] = KEY_2; sb[p] = 29; }   // Kth in [2.0, +inf)
      } else {
        int c1 = cnt16ge(u[p], KEY_1);
        if (c1 >= KTOP) {
          if (c1 == KTOP) { thr[p] = KEY_1; done[p] = true; sb[p] = 0; }
          else           { pfx[p] = KEY_1; sb[p] = 22; }  // Kth in [1.0, 2.0)
        } else {
          int c0 = cnt16ge(u[p], KEY_H);
          if (c0 >= KTOP) {
            if (c0 == KTOP) { thr[p] = KEY_H; done[p] = true; sb[p] = 0; }
            else           { pfx[p] = KEY_H; sb[p] = 22; } // Kth in [0.5, 1.0)
          } else {
            pfx[p] = 0u; sb[p] = 31;                       // rare: full descent
          }
        }
      }
    }
    int sbmax = sb[0];
#pragma unroll
    for (int p = 1; p < P; ++p) sbmax = sb[p] > sbmax ? sb[p] : sbmax;

    // ---- lockstep bit descent: 4 independent serial chains hide each other
    for (int bit = sbmax; bit >= 0; --bit) {
      bool alldone = true;
#pragma unroll
      for (int p = 0; p < P; ++p) {
        if (!done[p] && bit <= sb[p]) {
          const unsigned cand = pfx[p] | (1u << bit);
          const int c = cnt16ge(u[p], cand);
          if (c == KTOP)      { thr[p] = cand; done[p] = true; }
          else if (c > KTOP)  { pfx[p] = cand; }
        }
        alldone = alldone && done[p];
      }
      if (alldone) break;
    }
#pragma unroll
    for (int p = 0; p < P; ++p)
      if (!done[p]) thr[p] = pfx[p];

    // ---- epilogue: strict-greater sum + exact tie correction (v from key)
    float s[P];
    int cgt[P];
#pragma unroll
    for (int p = 0; p < P; ++p) {
      float sp = 0.f; int cg = 0;
#pragma unroll
      for (int i = 0; i < 16; ++i) {
        const unsigned ui = u[p][i];
        const bool gt = (ui > thr[p]);
        cg += (int)__popcll(__ballot(gt));
        const unsigned bbits = (ui & 0x80000000u) ? (ui ^ 0x80000000u) : ~ui;
        sp += gt ? __uint_as_float(bbits) : 0.f;
      }
      s[p] = sp; cgt[p] = cg;
    }
#pragma unroll
    for (int off = 32; off > 0; off >>= 1) {
#pragma unroll
      for (int p = 0; p < P; ++p) s[p] += __shfl_xor(s[p], off);
    }
#pragma unroll
    for (int p = 0; p < P; ++p) {
      const unsigned tb = (thr[p] & 0x80000000u) ? (thr[p] ^ 0x80000000u) : ~thr[p];
      const float tval = __uint_as_float(tb);
      const float extr = s[p] + (float)(KTOP - cgt[p]) * tval;
      if (lane == 0)
        out[(size_t)(b0 + g + p) * MDIM + m] = bv + fmaxf(extr - Tv, 0.f);
    }
  }
}

extern "C" void kernel_launch(void* const* d_in, const int* in_sizes, int n_in,
                              void* d_out, int out_size, void* d_ws, size_t ws_size,
                              hipStream_t stream) {
  const float* x    = (const float*)d_in[0];
  const float* w    = (const float*)d_in[1];
  const float* bias = (const float*)d_in[2];
  const float* T    = (const float*)d_in[3];
  float* out = (float*)d_out;

  // M * SPLIT waves = 8192 waves = 2048 blocks of 4 waves.
  dim3 grid(MDIM * SPLIT / 4);
  topk_sum_kernel<<<grid, dim3(256), 0, stream>>>(x, w, bias, T, out);
}